// Round 5
// baseline (1320.058 us; speedup 1.0000x reference)
//
#include <hip/hip_runtime.h>
#include <hip/hip_fp16.h>

#define B 32
#define NW2V 300
#define NR 200
#define NBLK 256          // blocks for count/scatter passes
#define MAXNB 2048        // max buckets (n_e <= 524288 -> 19-bit subj pack OK)

// r_T[j][b] = bias[j] + sum_k q[b][k] * W[k][j]   -> [N_R, B] layout, fp32
__global__ void compute_r_kernel(const float* __restrict__ q,
                                 const float* __restrict__ W,
                                 const float* __restrict__ bias,
                                 float* __restrict__ rT) {
    int tid = blockIdx.x * blockDim.x + threadIdx.x;
    if (tid >= NR * B) return;
    int b = tid & (B - 1);
    int j = tid >> 5;
    float acc = bias[j];
    for (int k = 0; k < NW2V; ++k)
        acc += q[b * NW2V + k] * W[k * NR + j];
    rT[j * B + b] = acc;
}

// x [B, N_E] f32 -> xT [N_E, B] f16, LDS-tiled, coalesced both sides
__global__ void transpose_in_kernel(const float* __restrict__ x,
                                    __half* __restrict__ xT, int n_e) {
    __shared__ float tile[64][33];
    int e0 = blockIdx.x * 64;
    for (int p = 0; p < 8; ++p) {
        int idx = p * 256 + threadIdx.x;
        int b = idx >> 6, e = idx & 63;
        if (e0 + e < n_e) tile[e][b] = x[(size_t)b * n_e + e0 + e];
    }
    __syncthreads();
    for (int p = 0; p < 8; ++p) {
        int idx = p * 256 + threadIdx.x;
        int b = idx & 31, e = idx >> 5;
        if (e0 + e < n_e) xT[(size_t)(e0 + e) * B + b] = __float2half(tile[e][b]);
    }
}

// ---- bucket sort (256 entities per bucket), indices shared by all 3 hops ----

// per-block LDS histogram over buckets -> hist_bb[bin*NBLK + blk]
__global__ void count_kernel(const int* __restrict__ obj,
                             int* __restrict__ hist_bb, int n_t, int nb, int chunk) {
    __shared__ int h[MAXNB];
    for (int i = threadIdx.x; i < nb; i += 256) h[i] = 0;
    __syncthreads();
    int t0 = blockIdx.x * chunk;
    int t1 = min(t0 + chunk, n_t);
    for (int t = t0 + threadIdx.x; t < t1; t += 256)
        atomicAdd(&h[obj[t] >> 8], 1);
    __syncthreads();
    for (int i = threadIdx.x; i < nb; i += 256)
        hist_bb[(size_t)i * NBLK + blockIdx.x] = h[i];
}

// scan phase A: per-256 block sums
__global__ void block_reduce_kernel(const int* __restrict__ vals,
                                    int* __restrict__ blockSums, int len) {
    __shared__ int s[256];
    int i = blockIdx.x * 256 + threadIdx.x;
    s[threadIdx.x] = (i < len) ? vals[i] : 0;
    __syncthreads();
    for (int off = 128; off > 0; off >>= 1) {
        if (threadIdx.x < off) s[threadIdx.x] += s[threadIdx.x + off];
        __syncthreads();
    }
    if (threadIdx.x == 0) blockSums[blockIdx.x] = s[0];
}

// scan phase B: single-block exclusive scan of blockSums[nb], nb <= 2048
__global__ void scan_blocksums_kernel(int* __restrict__ blockSums, int nb) {
    __shared__ int s[256];
    int t = threadIdx.x;
    int local[8];
    int run = 0;
    for (int c = 0; c < 8; ++c) {
        int j = t * 8 + c;
        run += (j < nb) ? blockSums[j] : 0;
        local[c] = run;                         // inclusive within thread
    }
    s[t] = run;
    __syncthreads();
    for (int off = 1; off < 256; off <<= 1) {
        int v = (t >= off) ? s[t - off] : 0;
        __syncthreads();
        s[t] += v;
        __syncthreads();
    }
    int threadExcl = s[t] - run;
    for (int c = 0; c < 8; ++c) {
        int j = t * 8 + c;
        if (j < nb) blockSums[j] = threadExcl + (c == 0 ? 0 : local[c - 1]);
    }
}

// scan phase C: base_bb = exclusive scan of hist_bb
__global__ void scan_apply_kernel(const int* __restrict__ vals,
                                  const int* __restrict__ blockSums,
                                  int* __restrict__ out, int len) {
    __shared__ int s[256];
    int t = threadIdx.x;
    int i = blockIdx.x * 256 + t;
    int c = (i < len) ? vals[i] : 0;
    s[t] = c;
    __syncthreads();
    for (int off = 1; off < 256; off <<= 1) {
        int v = (t >= off) ? s[t - off] : 0;
        __syncthreads();
        s[t] += v;
        __syncthreads();
    }
    if (i < len) out[i] = blockSums[blockIdx.x] + s[t] - c;
}

// rank via LDS hist, write 8B entries into (bin,block)-contiguous runs
__global__ void scatter8_kernel(const int* __restrict__ subj,
                                const int* __restrict__ rel,
                                const int* __restrict__ obj,
                                const int* __restrict__ base_bb,
                                uint2* __restrict__ packed2,
                                int n_t, int nb, int chunk) {
    __shared__ int h[MAXNB];
    __shared__ int sbase[MAXNB];
    for (int i = threadIdx.x; i < nb; i += 256) {
        h[i] = 0;
        sbase[i] = base_bb[(size_t)i * NBLK + blockIdx.x];
    }
    __syncthreads();
    int t0 = blockIdx.x * chunk;
    int t1 = min(t0 + chunk, n_t);
    for (int t = t0 + threadIdx.x; t < t1; t += 256) {
        int o = obj[t];
        int bin = o >> 8;
        int rank = atomicAdd(&h[bin], 1);
        int pos = sbase[bin] + rank;
        packed2[pos] = make_uint2((unsigned)subj[t] | ((unsigned)rel[t] << 19),
                                  (unsigned)o);
    }
}

// One follow step: one block per 256-entity bucket. Independent gathers (full
// MLP), fp32 LDS accumulation (ds_add_f32, padded stride 33), single coalesced
// store. final_out=1 -> write fp32 [B, N_E] directly (fused transpose_out).
__global__ void hop_bucket_kernel(const __half2* __restrict__ xT2,
                                  const float2* __restrict__ rT2,
                                  __half2* __restrict__ outT2,
                                  float* __restrict__ out_f32,
                                  const uint2* __restrict__ packed2,
                                  const int* __restrict__ base_bb,
                                  const int* __restrict__ n_hop,
                                  int hop, int n_e, int n_t, int final_out) {
    __shared__ float acc[256 * 33];
    int bin = blockIdx.x;
    int e0  = bin << 8;
    int tid = threadIdx.x;

    if (*n_hop >= hop) {
        for (int i = tid; i < 256 * 33; i += 256) acc[i] = 0.f;
        __syncthreads();
        int beg = base_bb[(size_t)bin * NBLK];
        int end = (bin + 1 < gridDim.x) ? base_bb[(size_t)(bin + 1) * NBLK] : n_t;
        int g = tid >> 4, l = tid & 15;
        for (int p = beg + g; p < end; p += 16) {
            uint2 e = packed2[p];                 // broadcast within 16-lane group
            int s  = e.x & 0x7FFFF;
            int r  = e.x >> 19;
            int el = e.y & 255;
            __half2 xh = xT2[(size_t)s * 16 + l]; // one 64B line per group
            float2  rf = rT2[(size_t)r * 16 + l]; // L1-resident
            float2  xf = __half22float2(xh);
            atomicAdd(&acc[el * 33 + 2 * l],     xf.x * rf.x);
            atomicAdd(&acc[el * 33 + 2 * l + 1], xf.y * rf.y);
        }
        __syncthreads();
        if (final_out) {
            int e = tid;
            if (e0 + e < n_e)
                for (int b = 0; b < 32; ++b)
                    out_f32[(size_t)b * n_e + e0 + e] = acc[e * 33 + b];
        } else {
            for (int i = tid; i < 4096; i += 256) {
                int e = i >> 4, l2 = i & 15;
                if (e0 + e < n_e)
                    outT2[(size_t)(e0 + e) * 16 + l2] =
                        __floats2half2_rn(acc[e * 33 + 2 * l2], acc[e * 33 + 2 * l2 + 1]);
            }
        }
    } else {                                      // degenerate: identity
        if (final_out) {
            int e = tid;
            if (e0 + e < n_e)
                for (int b = 0; b < 32; ++b) {
                    __half2 xh = xT2[(size_t)(e0 + e) * 16 + (b >> 1)];
                    out_f32[(size_t)b * n_e + e0 + e] =
                        (b & 1) ? __high2float(xh) : __low2float(xh);
                }
        } else {
            for (int i = tid; i < 4096; i += 256) {
                int e = i >> 4, l2 = i & 15;
                if (e0 + e < n_e)
                    outT2[(size_t)(e0 + e) * 16 + l2] = xT2[(size_t)(e0 + e) * 16 + l2];
            }
        }
    }
}

extern "C" void kernel_launch(void* const* d_in, const int* in_sizes, int n_in,
                              void* d_out, int out_size, void* d_ws, size_t ws_size,
                              hipStream_t stream) {
    const float* x    = (const float*)d_in[0];
    const float* q    = (const float*)d_in[1];
    const int*   subj = (const int*)d_in[2];
    const int*   rel  = (const int*)d_in[3];
    const int*   obj  = (const int*)d_in[4];
    const float* W1   = (const float*)d_in[5];
    const float* bb1  = (const float*)d_in[6];
    const float* W2   = (const float*)d_in[7];
    const float* bb2  = (const float*)d_in[8];
    const float* W3   = (const float*)d_in[9];
    const float* bb3  = (const float*)d_in[10];
    const int*   n_hop = (const int*)d_in[11];
    float* out = (float*)d_out;

    const int n_e   = in_sizes[0] / B;        // 500000
    const int n_t   = in_sizes[2];            // 2000000
    const int nb    = (n_e + 255) >> 8;       // 1954 buckets (<= MAXNB)
    const int chunk = (n_t + NBLK - 1) / NBLK;
    const int scanLen = nb * NBLK;            // 500224
    const int snb   = (scanLen + 255) / 256;  // 1954 (<= 2048)

    // ws layout (~84 MB of 128 MB):
    __half* bufA    = (__half*)d_ws;                      // [N_E, B] f16, 32 MB
    __half* bufB    = bufA + (size_t)n_e * B;             // [N_E, B] f16, 32 MB
    float*  rT      = (float*)(bufB + (size_t)n_e * B);   // 3*[N_R,B] f32
    int*    hist_bb = (int*)(rT + 3 * NR * B);            // [nb*NBLK]
    int*    base_bb = hist_bb + scanLen;                  // [nb*NBLK]
    int*    bsums   = base_bb + scanLen;                  // [snb]
    uint2*  packed2 = (uint2*)(bsums + snb);              // [N_T], 16 MB

    const int rblocks = (NR * B + 255) / 256;
    compute_r_kernel<<<rblocks, 256, 0, stream>>>(q, W1, bb1, rT + 0 * NR * B);
    compute_r_kernel<<<rblocks, 256, 0, stream>>>(q, W2, bb2, rT + 1 * NR * B);
    compute_r_kernel<<<rblocks, 256, 0, stream>>>(q, W3, bb3, rT + 2 * NR * B);

    const int tblocks = (n_e + 63) / 64;
    transpose_in_kernel<<<tblocks, 256, 0, stream>>>(x, bufA, n_e);

    // --- bucket sort by obj>>8 (once; shared by all 3 hops) ---
    count_kernel<<<NBLK, 256, 0, stream>>>(obj, hist_bb, n_t, nb, chunk);
    block_reduce_kernel<<<snb, 256, 0, stream>>>(hist_bb, bsums, scanLen);
    scan_blocksums_kernel<<<1, 256, 0, stream>>>(bsums, snb);
    scan_apply_kernel<<<snb, 256, 0, stream>>>(hist_bb, bsums, base_bb, scanLen);
    scatter8_kernel<<<NBLK, 256, 0, stream>>>(subj, rel, obj, base_bb, packed2,
                                              n_t, nb, chunk);

    // --- 3 atomic-free hops; hop 3 writes fp32 [B,N_E] directly (fused) ---
    hop_bucket_kernel<<<nb, 256, 0, stream>>>((const __half2*)bufA, (const float2*)(rT + 0 * NR * B),
                                              (__half2*)bufB, nullptr,
                                              packed2, base_bb, n_hop, 1, n_e, n_t, 0);
    hop_bucket_kernel<<<nb, 256, 0, stream>>>((const __half2*)bufB, (const float2*)(rT + 1 * NR * B),
                                              (__half2*)bufA, nullptr,
                                              packed2, base_bb, n_hop, 2, n_e, n_t, 0);
    hop_bucket_kernel<<<nb, 256, 0, stream>>>((const __half2*)bufA, (const float2*)(rT + 2 * NR * B),
                                              nullptr, out,
                                              packed2, base_bb, n_hop, 3, n_e, n_t, 1);
}

// Round 6
// 764.938 us; speedup vs baseline: 1.7257x; 1.7257x over previous
//
#include <hip/hip_runtime.h>
#include <hip/hip_fp16.h>

#define B 32
#define NW2V 300
#define NR 200
#define NBLK 128          // chunks for count/scatter passes (runs of ~16 = 128B)
#define MAXNB 2048        // max coarse buckets

// r_T[j][b] = bias[j] + sum_k q[b][k] * W[k][j]   -> [N_R, B] layout, fp32
__global__ void compute_r_kernel(const float* __restrict__ q,
                                 const float* __restrict__ W,
                                 const float* __restrict__ bias,
                                 float* __restrict__ rT) {
    int tid = blockIdx.x * blockDim.x + threadIdx.x;
    if (tid >= NR * B) return;
    int b = tid & (B - 1);
    int j = tid >> 5;
    float acc = bias[j];
    for (int k = 0; k < NW2V; ++k)
        acc += q[b * NW2V + k] * W[k * NR + j];
    rT[j * B + b] = acc;
}

// x [B, N_E] f32 -> xT [N_E, B] f16
__global__ void transpose_in_kernel(const float* __restrict__ x,
                                    __half* __restrict__ xT, int n_e) {
    __shared__ float tile[64][33];
    int e0 = blockIdx.x * 64;
    for (int p = 0; p < 8; ++p) {
        int idx = p * 256 + threadIdx.x;
        int b = idx >> 6, e = idx & 63;
        if (e0 + e < n_e) tile[e][b] = x[(size_t)b * n_e + e0 + e];
    }
    __syncthreads();
    for (int p = 0; p < 8; ++p) {
        int idx = p * 256 + threadIdx.x;
        int b = idx & 31, e = idx >> 5;
        if (e0 + e < n_e) xT[(size_t)(e0 + e) * B + b] = __float2half(tile[e][b]);
    }
}

// xT [N_E, B] f16 -> out [B, N_E] f32
__global__ void transpose_out_kernel(const __half* __restrict__ xT,
                                     float* __restrict__ out, int n_e) {
    __shared__ float tile[64][33];
    int e0 = blockIdx.x * 64;
    for (int p = 0; p < 8; ++p) {
        int idx = p * 256 + threadIdx.x;
        int b = idx & 31, e = idx >> 5;
        if (e0 + e < n_e) tile[e][b] = __half2float(xT[(size_t)(e0 + e) * B + b]);
    }
    __syncthreads();
    for (int p = 0; p < 8; ++p) {
        int idx = p * 256 + threadIdx.x;
        int b = idx >> 6, e = idx & 63;
        if (e0 + e < n_e) out[(size_t)b * n_e + e0 + e] = tile[e][b];
    }
}

// ---- two-level sort of triples by obj (shared by all 3 hops) ----

__global__ void count_kernel(const int* __restrict__ obj,
                             int* __restrict__ hist_bb, int n_t, int nb, int chunk) {
    __shared__ int h[MAXNB];
    for (int i = threadIdx.x; i < nb; i += 256) h[i] = 0;
    __syncthreads();
    int t0 = blockIdx.x * chunk;
    int t1 = min(t0 + chunk, n_t);
    for (int t = t0 + threadIdx.x; t < t1; t += 256)
        atomicAdd(&h[obj[t] >> 8], 1);
    __syncthreads();
    for (int i = threadIdx.x; i < nb; i += 256)
        hist_bb[(size_t)i * NBLK + blockIdx.x] = h[i];
}

__global__ void block_reduce_kernel(const int* __restrict__ vals,
                                    int* __restrict__ blockSums, int len) {
    __shared__ int s[256];
    int i = blockIdx.x * 256 + threadIdx.x;
    s[threadIdx.x] = (i < len) ? vals[i] : 0;
    __syncthreads();
    for (int off = 128; off > 0; off >>= 1) {
        if (threadIdx.x < off) s[threadIdx.x] += s[threadIdx.x + off];
        __syncthreads();
    }
    if (threadIdx.x == 0) blockSums[blockIdx.x] = s[0];
}

__global__ void scan_blocksums_kernel(int* __restrict__ blockSums, int nb) {
    __shared__ int s[256];
    int t = threadIdx.x;
    int local[8];
    int run = 0;
    for (int c = 0; c < 8; ++c) {
        int j = t * 8 + c;
        run += (j < nb) ? blockSums[j] : 0;
        local[c] = run;
    }
    s[t] = run;
    __syncthreads();
    for (int off = 1; off < 256; off <<= 1) {
        int v = (t >= off) ? s[t - off] : 0;
        __syncthreads();
        s[t] += v;
        __syncthreads();
    }
    int threadExcl = s[t] - run;
    for (int c = 0; c < 8; ++c) {
        int j = t * 8 + c;
        if (j < nb) blockSums[j] = threadExcl + (c == 0 ? 0 : local[c - 1]);
    }
}

__global__ void scan_apply_kernel(const int* __restrict__ vals,
                                  const int* __restrict__ blockSums,
                                  int* __restrict__ out, int len) {
    __shared__ int s[256];
    int t = threadIdx.x;
    int i = blockIdx.x * 256 + t;
    int c = (i < len) ? vals[i] : 0;
    s[t] = c;
    __syncthreads();
    for (int off = 1; off < 256; off <<= 1) {
        int v = (t >= off) ? s[t - off] : 0;
        __syncthreads();
        s[t] += v;
        __syncthreads();
    }
    if (i < len) out[i] = blockSums[blockIdx.x] + s[t] - c;
}

// coarse scatter into 256-entity buckets; (bin,blk) runs avg 16 entries = 128B
__global__ void scatter8_kernel(const int* __restrict__ subj,
                                const int* __restrict__ rel,
                                const int* __restrict__ obj,
                                const int* __restrict__ base_bb,
                                uint2* __restrict__ packed2,
                                int n_t, int nb, int chunk) {
    __shared__ int h[MAXNB];
    __shared__ int sbase[MAXNB];
    for (int i = threadIdx.x; i < nb; i += 256) {
        h[i] = 0;
        sbase[i] = base_bb[(size_t)i * NBLK + blockIdx.x];
    }
    __syncthreads();
    int t0 = blockIdx.x * chunk;
    int t1 = min(t0 + chunk, n_t);
    for (int t = t0 + threadIdx.x; t < t1; t += 256) {
        int o = obj[t];
        int bin = o >> 8;
        int rank = atomicAdd(&h[bin], 1);
        packed2[sbase[bin] + rank] = make_uint2(
            (unsigned)subj[t] | ((unsigned)rel[t] << 19), (unsigned)o);
    }
}

// fine counting sort by obj&255 within each bucket -> fully obj-sorted
__global__ void fine_sort_kernel(const uint2* __restrict__ in,
                                 uint2* __restrict__ outp,
                                 const int* __restrict__ base_bb,
                                 int n_t, int nb) {
    __shared__ int cnt[256];
    __shared__ int cur[256];
    int bin = blockIdx.x;
    int beg = base_bb[(size_t)bin * NBLK];
    int end = (bin + 1 < nb) ? base_bb[(size_t)(bin + 1) * NBLK] : n_t;
    int t = threadIdx.x;
    cnt[t] = 0;
    __syncthreads();
    for (int i = beg + t; i < end; i += 256)
        atomicAdd(&cnt[in[i].y & 255], 1);
    __syncthreads();
    int c = cnt[t];
    __syncthreads();
    for (int off = 1; off < 256; off <<= 1) {
        int v = (t >= off) ? cnt[t - off] : 0;
        __syncthreads();
        cnt[t] += v;
        __syncthreads();
    }
    cur[t] = cnt[t] - c + beg;        // exclusive scan + bucket base
    __syncthreads();
    for (int i = beg + t; i < end; i += 256) {
        uint2 e = in[i];
        int pos = atomicAdd(&cur[e.y & 255], 1);
        outp[pos] = e;
    }
}

// Flat hop over SORTED triples: 16-lane group handles 16 consecutive entries.
// Phase 1: 16 independent gathers (full MLP). Phase 2: fp32 run-merge, one
// packed-f16 atomic per equal-obj run (~0.29x of round-3's atomic count).
__global__ void hop_merge_kernel(const __half2* __restrict__ xT2,
                                 const float2* __restrict__ rT2,
                                 __half2* __restrict__ outT2,
                                 const uint2* __restrict__ sorted2,
                                 const int* __restrict__ n_hop,
                                 int hop, int n_e, int n_t) {
    int tid = threadIdx.x;
    if (*n_hop < hop) {               // degenerate: identity copy
        long total = (long)n_e * 16;
        for (long i = (long)blockIdx.x * 256 + tid; i < total;
             i += (long)gridDim.x * 256)
            outT2[i] = xT2[i];
        return;
    }
    __shared__ uint2 ent[256];
    int base = blockIdx.x * 256;
    int cnt = min(256, n_t - base);
    ent[tid] = (tid < cnt) ? sorted2[base + tid]
                           : make_uint2(0u, 0xFFFFFFFFu);
    __syncthreads();
    int g = tid >> 4, l = tid & 15;
    int e0 = g * 16;
    int m = min(16, cnt - e0);
    if (m <= 0) return;

    __half2 xh[16];
#pragma unroll
    for (int j = 0; j < 16; ++j) {    // independent gathers, all in flight
        int s = (int)(ent[e0 + j].x & 0x7FFFF);
        xh[j] = xT2[(size_t)s * 16 + l];
    }

    float a0 = 0.f, a1 = 0.f;
    unsigned cur_o = ent[e0].y;
    for (int j = 0; j < m; ++j) {
        uint2 e = ent[e0 + j];
        int r = (int)(e.x >> 19);
        float2 rf = rT2[(size_t)r * 16 + l];     // L1-resident table
        float2 xf = __half22float2(xh[j]);
        if (e.y != cur_o) {                      // uniform within 16-lane group
            unsafeAtomicAdd(&outT2[(size_t)cur_o * 16 + l],
                            __floats2half2_rn(a0, a1));
            a0 = 0.f; a1 = 0.f;
            cur_o = e.y;
        }
        a0 += xf.x * rf.x;
        a1 += xf.y * rf.y;
    }
    unsafeAtomicAdd(&outT2[(size_t)cur_o * 16 + l], __floats2half2_rn(a0, a1));
}

extern "C" void kernel_launch(void* const* d_in, const int* in_sizes, int n_in,
                              void* d_out, int out_size, void* d_ws, size_t ws_size,
                              hipStream_t stream) {
    const float* x    = (const float*)d_in[0];
    const float* q    = (const float*)d_in[1];
    const int*   subj = (const int*)d_in[2];
    const int*   rel  = (const int*)d_in[3];
    const int*   obj  = (const int*)d_in[4];
    const float* W1   = (const float*)d_in[5];
    const float* bb1  = (const float*)d_in[6];
    const float* W2   = (const float*)d_in[7];
    const float* bb2  = (const float*)d_in[8];
    const float* W3   = (const float*)d_in[9];
    const float* bb3  = (const float*)d_in[10];
    const int*   n_hop = (const int*)d_in[11];
    float* out = (float*)d_out;

    const int n_e   = in_sizes[0] / B;        // 500000
    const int n_t   = in_sizes[2];            // 2000000
    const int nb    = (n_e + 255) >> 8;       // 1954 coarse buckets
    const int chunk = (n_t + NBLK - 1) / NBLK;
    const int scanLen = nb * NBLK;            // 250112
    const int snb   = (scanLen + 255) / 256;  // 977 (<= 2048)

    // ws layout (all 64B-aligned chunks, ~98 MB of >=128 MB):
    char* w = (char*)d_ws;
    __half* bufA    = (__half*)w;                     w += 32000000;  // [N_E,B] f16
    __half* bufB    = (__half*)w;                     w += 32000000;  // [N_E,B] f16
    float*  rT      = (float*)w;                      w += 76800;     // 3*[N_R,B]
    int*    hist_bb = (int*)w;                        w += 1000448;   // [nb*NBLK]
    int*    base_bb = (int*)w;                        w += 1000448;   // [nb*NBLK]
    int*    bsums   = (int*)w;                        w += 4096;      // [<=1024]
    uint2*  packed2 = (uint2*)w;                      w += 16000000;  // [N_T]
    uint2*  sorted2 = (uint2*)w;                                      // [N_T]

    const int rblocks = (NR * B + 255) / 256;
    compute_r_kernel<<<rblocks, 256, 0, stream>>>(q, W1, bb1, rT + 0 * NR * B);
    compute_r_kernel<<<rblocks, 256, 0, stream>>>(q, W2, bb2, rT + 1 * NR * B);
    compute_r_kernel<<<rblocks, 256, 0, stream>>>(q, W3, bb3, rT + 2 * NR * B);

    const int tblocks = (n_e + 63) / 64;
    transpose_in_kernel<<<tblocks, 256, 0, stream>>>(x, bufA, n_e);

    // --- sort by obj (once) ---
    count_kernel<<<NBLK, 256, 0, stream>>>(obj, hist_bb, n_t, nb, chunk);
    block_reduce_kernel<<<snb, 256, 0, stream>>>(hist_bb, bsums, scanLen);
    scan_blocksums_kernel<<<1, 256, 0, stream>>>(bsums, snb);
    scan_apply_kernel<<<snb, 256, 0, stream>>>(hist_bb, bsums, base_bb, scanLen);
    scatter8_kernel<<<NBLK, 256, 0, stream>>>(subj, rel, obj, base_bb, packed2,
                                              n_t, nb, chunk);
    fine_sort_kernel<<<nb, 256, 0, stream>>>(packed2, sorted2, base_bb, n_t, nb);

    // --- 3 flat hops with run-merged atomics ---
    const int hblocks = (n_t + 255) / 256;    // 7813
    const size_t bytes = (size_t)n_e * B * sizeof(__half);

    hipMemsetAsync(bufB, 0, bytes, stream);
    hop_merge_kernel<<<hblocks, 256, 0, stream>>>((const __half2*)bufA,
        (const float2*)(rT + 0 * NR * B), (__half2*)bufB, sorted2, n_hop, 1, n_e, n_t);
    hipMemsetAsync(bufA, 0, bytes, stream);
    hop_merge_kernel<<<hblocks, 256, 0, stream>>>((const __half2*)bufB,
        (const float2*)(rT + 1 * NR * B), (__half2*)bufA, sorted2, n_hop, 2, n_e, n_t);
    hipMemsetAsync(bufB, 0, bytes, stream);
    hop_merge_kernel<<<hblocks, 256, 0, stream>>>((const __half2*)bufA,
        (const float2*)(rT + 2 * NR * B), (__half2*)bufB, sorted2, n_hop, 3, n_e, n_t);

    transpose_out_kernel<<<tblocks, 256, 0, stream>>>(bufB, out, n_e);
}

// Round 7
// 516.925 us; speedup vs baseline: 2.5537x; 1.4798x over previous
//
#include <hip/hip_runtime.h>
#include <hip/hip_fp16.h>

#define B 32
#define NW2V 300
#define NR 200
#define NBLK 256          // chunks for count/scatter passes
#define MAXNB 2048        // max coarse buckets

// r_T[j][b] = bias[j] + sum_k q[b][k] * W[k][j]   -> [N_R, B] layout, fp32
__global__ void compute_r_kernel(const float* __restrict__ q,
                                 const float* __restrict__ W,
                                 const float* __restrict__ bias,
                                 float* __restrict__ rT) {
    int tid = blockIdx.x * blockDim.x + threadIdx.x;
    if (tid >= NR * B) return;
    int b = tid & (B - 1);
    int j = tid >> 5;
    float acc = bias[j];
    for (int k = 0; k < NW2V; ++k)
        acc += q[b * NW2V + k] * W[k * NR + j];
    rT[j * B + b] = acc;
}

// x [B, N_E] f32 -> xT [N_E, B] f16
__global__ void transpose_in_kernel(const float* __restrict__ x,
                                    __half* __restrict__ xT, int n_e) {
    __shared__ float tile[64][33];
    int e0 = blockIdx.x * 64;
    for (int p = 0; p < 8; ++p) {
        int idx = p * 256 + threadIdx.x;
        int b = idx >> 6, e = idx & 63;
        if (e0 + e < n_e) tile[e][b] = x[(size_t)b * n_e + e0 + e];
    }
    __syncthreads();
    for (int p = 0; p < 8; ++p) {
        int idx = p * 256 + threadIdx.x;
        int b = idx & 31, e = idx >> 5;
        if (e0 + e < n_e) xT[(size_t)(e0 + e) * B + b] = __float2half(tile[e][b]);
    }
}

// xT [N_E, B] f16 -> out [B, N_E] f32
__global__ void transpose_out_kernel(const __half* __restrict__ xT,
                                     float* __restrict__ out, int n_e) {
    __shared__ float tile[64][33];
    int e0 = blockIdx.x * 64;
    for (int p = 0; p < 8; ++p) {
        int idx = p * 256 + threadIdx.x;
        int b = idx & 31, e = idx >> 5;
        if (e0 + e < n_e) tile[e][b] = __half2float(xT[(size_t)(e0 + e) * B + b]);
    }
    __syncthreads();
    for (int p = 0; p < 8; ++p) {
        int idx = p * 256 + threadIdx.x;
        int b = idx >> 6, e = idx & 63;
        if (e0 + e < n_e) out[(size_t)b * n_e + e0 + e] = tile[e][b];
    }
}

// ---- two-level sort of triples by obj (shared by all 3 hops) ----

__global__ void count_kernel(const int* __restrict__ obj,
                             int* __restrict__ hist_bb, int n_t, int nb, int chunk) {
    __shared__ int h[MAXNB];
    for (int i = threadIdx.x; i < nb; i += 256) h[i] = 0;
    __syncthreads();
    int t0 = blockIdx.x * chunk;
    int t1 = min(t0 + chunk, n_t);
    for (int t = t0 + threadIdx.x; t < t1; t += 256)
        atomicAdd(&h[obj[t] >> 8], 1);
    __syncthreads();
    for (int i = threadIdx.x; i < nb; i += 256)
        hist_bb[(size_t)i * NBLK + blockIdx.x] = h[i];
}

__global__ void block_reduce_kernel(const int* __restrict__ vals,
                                    int* __restrict__ blockSums, int len) {
    __shared__ int s[256];
    int i = blockIdx.x * 256 + threadIdx.x;
    s[threadIdx.x] = (i < len) ? vals[i] : 0;
    __syncthreads();
    for (int off = 128; off > 0; off >>= 1) {
        if (threadIdx.x < off) s[threadIdx.x] += s[threadIdx.x + off];
        __syncthreads();
    }
    if (threadIdx.x == 0) blockSums[blockIdx.x] = s[0];
}

__global__ void scan_blocksums_kernel(int* __restrict__ blockSums, int nb) {
    __shared__ int s[256];
    int t = threadIdx.x;
    int local[8];
    int run = 0;
    for (int c = 0; c < 8; ++c) {
        int j = t * 8 + c;
        run += (j < nb) ? blockSums[j] : 0;
        local[c] = run;
    }
    s[t] = run;
    __syncthreads();
    for (int off = 1; off < 256; off <<= 1) {
        int v = (t >= off) ? s[t - off] : 0;
        __syncthreads();
        s[t] += v;
        __syncthreads();
    }
    int threadExcl = s[t] - run;
    for (int c = 0; c < 8; ++c) {
        int j = t * 8 + c;
        if (j < nb) blockSums[j] = threadExcl + (c == 0 ? 0 : local[c - 1]);
    }
}

__global__ void scan_apply_kernel(const int* __restrict__ vals,
                                  const int* __restrict__ blockSums,
                                  int* __restrict__ out, int len) {
    __shared__ int s[256];
    int t = threadIdx.x;
    int i = blockIdx.x * 256 + t;
    int c = (i < len) ? vals[i] : 0;
    s[t] = c;
    __syncthreads();
    for (int off = 1; off < 256; off <<= 1) {
        int v = (t >= off) ? s[t - off] : 0;
        __syncthreads();
        s[t] += v;
        __syncthreads();
    }
    if (i < len) out[i] = blockSums[blockIdx.x] + s[t] - c;
}

// coarse scatter into 256-entity buckets
__global__ void scatter8_kernel(const int* __restrict__ subj,
                                const int* __restrict__ rel,
                                const int* __restrict__ obj,
                                const int* __restrict__ base_bb,
                                uint2* __restrict__ packed2,
                                int n_t, int nb, int chunk) {
    __shared__ int h[MAXNB];
    __shared__ int sbase[MAXNB];
    for (int i = threadIdx.x; i < nb; i += 256) {
        h[i] = 0;
        sbase[i] = base_bb[(size_t)i * NBLK + blockIdx.x];
    }
    __syncthreads();
    int t0 = blockIdx.x * chunk;
    int t1 = min(t0 + chunk, n_t);
    for (int t = t0 + threadIdx.x; t < t1; t += 256) {
        int o = obj[t];
        int bin = o >> 8;
        int rank = atomicAdd(&h[bin], 1);
        packed2[sbase[bin] + rank] = make_uint2(
            (unsigned)subj[t] | ((unsigned)rel[t] << 19), (unsigned)o);
    }
}

// fine counting sort by obj&255 within each bucket -> fully obj-sorted
__global__ void fine_sort_kernel(const uint2* __restrict__ in,
                                 uint2* __restrict__ outp,
                                 const int* __restrict__ base_bb,
                                 int n_t, int nb) {
    __shared__ int cnt[256];
    __shared__ int cur[256];
    int bin = blockIdx.x;
    int beg = base_bb[(size_t)bin * NBLK];
    int end = (bin + 1 < nb) ? base_bb[(size_t)(bin + 1) * NBLK] : n_t;
    int t = threadIdx.x;
    cnt[t] = 0;
    __syncthreads();
    for (int i = beg + t; i < end; i += 256)
        atomicAdd(&cnt[in[i].y & 255], 1);
    __syncthreads();
    int c = cnt[t];
    __syncthreads();
    for (int off = 1; off < 256; off <<= 1) {
        int v = (t >= off) ? cnt[t - off] : 0;
        __syncthreads();
        cnt[t] += v;
        __syncthreads();
    }
    cur[t] = cnt[t] - c + beg;        // exclusive scan + bucket base
    __syncthreads();
    for (int i = beg + t; i < end; i += 256) {
        uint2 e = in[i];
        int pos = atomicAdd(&cur[e.y & 255], 1);
        outp[pos] = e;
    }
}

// Flat hop over SORTED triples: 16-lane group handles 16 consecutive entries.
// FULLY UNROLLED with compile-time xh[] indices so the per-thread array stays
// in VGPRs (round-6 bug: runtime-bounded loop -> promote-alloca demoted xh to
// LDS: 66KB/block, 18% occupancy, 1.9e7 bank conflicts). Tail groups are
// padded to 16 with sentinel obj and masked via `if (j < m)`.
__global__ void hop_merge_kernel(const __half2* __restrict__ xT2,
                                 const float2* __restrict__ rT2,
                                 __half2* __restrict__ outT2,
                                 const uint2* __restrict__ sorted2,
                                 const int* __restrict__ n_hop,
                                 int hop, int n_e, int n_t) {
    int tid = threadIdx.x;
    if (*n_hop < hop) {               // degenerate: identity copy
        long total = (long)n_e * 16;
        for (long i = (long)blockIdx.x * 256 + tid; i < total;
             i += (long)gridDim.x * 256)
            outT2[i] = xT2[i];
        return;
    }
    __shared__ uint2 ent[256];
    int base = blockIdx.x * 256;
    int cnt = min(256, n_t - base);
    ent[tid] = (tid < cnt) ? sorted2[base + tid]
                           : make_uint2(0u, 0xFFFFFFFFu);
    __syncthreads();
    int g = tid >> 4, l = tid & 15;
    int e0 = g * 16;
    int m = min(16, cnt - e0);        // group-uniform
    if (m <= 0) return;

    __half2 xh[16];
#pragma unroll
    for (int j = 0; j < 16; ++j) {    // independent gathers, all in flight
        int s = (int)(ent[e0 + j].x & 0x7FFFF);
        xh[j] = xT2[(size_t)s * 16 + l];
    }

    float a0 = 0.f, a1 = 0.f;
    unsigned cur_o = ent[e0].y;
#pragma unroll
    for (int j = 0; j < 16; ++j) {
        if (j < m) {
            uint2 e = ent[e0 + j];
            float2 rf = rT2[(size_t)(e.x >> 19) * 16 + l];   // L1-resident
            float2 xf = __half22float2(xh[j]);
            if (e.y != cur_o) {                  // uniform within 16-lane group
                unsafeAtomicAdd(&outT2[(size_t)cur_o * 16 + l],
                                __floats2half2_rn(a0, a1));
                a0 = 0.f; a1 = 0.f;
                cur_o = e.y;
            }
            a0 += xf.x * rf.x;
            a1 += xf.y * rf.y;
        }
    }
    unsafeAtomicAdd(&outT2[(size_t)cur_o * 16 + l], __floats2half2_rn(a0, a1));
}

extern "C" void kernel_launch(void* const* d_in, const int* in_sizes, int n_in,
                              void* d_out, int out_size, void* d_ws, size_t ws_size,
                              hipStream_t stream) {
    const float* x    = (const float*)d_in[0];
    const float* q    = (const float*)d_in[1];
    const int*   subj = (const int*)d_in[2];
    const int*   rel  = (const int*)d_in[3];
    const int*   obj  = (const int*)d_in[4];
    const float* W1   = (const float*)d_in[5];
    const float* bb1  = (const float*)d_in[6];
    const float* W2   = (const float*)d_in[7];
    const float* bb2  = (const float*)d_in[8];
    const float* W3   = (const float*)d_in[9];
    const float* bb3  = (const float*)d_in[10];
    const int*   n_hop = (const int*)d_in[11];
    float* out = (float*)d_out;

    const int n_e   = in_sizes[0] / B;        // 500000
    const int n_t   = in_sizes[2];            // 2000000
    const int nb    = (n_e + 255) >> 8;       // 1954 coarse buckets
    const int chunk = (n_t + NBLK - 1) / NBLK;
    const int scanLen = nb * NBLK;            // 500224
    const int snb   = (scanLen + 255) / 256;  // 1954 (<= 2048)

    // ws layout (~102 MB of >=128 MB):
    char* w = (char*)d_ws;
    __half* bufA    = (__half*)w;                     w += 32000000;  // [N_E,B] f16
    __half* bufB    = (__half*)w;                     w += 32000000;  // [N_E,B] f16
    float*  rT      = (float*)w;                      w += 76800;     // 3*[N_R,B]
    int*    hist_bb = (int*)w;                        w += 2097152;   // [nb*NBLK]
    int*    base_bb = (int*)w;                        w += 2097152;   // [nb*NBLK]
    int*    bsums   = (int*)w;                        w += 16384;     // [snb]
    uint2*  packed2 = (uint2*)w;                      w += 16000000;  // [N_T]
    uint2*  sorted2 = (uint2*)w;                                      // [N_T]

    const int rblocks = (NR * B + 255) / 256;
    compute_r_kernel<<<rblocks, 256, 0, stream>>>(q, W1, bb1, rT + 0 * NR * B);
    compute_r_kernel<<<rblocks, 256, 0, stream>>>(q, W2, bb2, rT + 1 * NR * B);
    compute_r_kernel<<<rblocks, 256, 0, stream>>>(q, W3, bb3, rT + 2 * NR * B);

    const int tblocks = (n_e + 63) / 64;
    transpose_in_kernel<<<tblocks, 256, 0, stream>>>(x, bufA, n_e);

    // --- sort by obj (once) ---
    count_kernel<<<NBLK, 256, 0, stream>>>(obj, hist_bb, n_t, nb, chunk);
    block_reduce_kernel<<<snb, 256, 0, stream>>>(hist_bb, bsums, scanLen);
    scan_blocksums_kernel<<<1, 256, 0, stream>>>(bsums, snb);
    scan_apply_kernel<<<snb, 256, 0, stream>>>(hist_bb, bsums, base_bb, scanLen);
    scatter8_kernel<<<NBLK, 256, 0, stream>>>(subj, rel, obj, base_bb, packed2,
                                              n_t, nb, chunk);
    fine_sort_kernel<<<nb, 256, 0, stream>>>(packed2, sorted2, base_bb, n_t, nb);

    // --- 3 flat hops with run-merged atomics ---
    const int hblocks = (n_t + 255) / 256;    // 7813
    const size_t bytes = (size_t)n_e * B * sizeof(__half);

    hipMemsetAsync(bufB, 0, bytes, stream);
    hop_merge_kernel<<<hblocks, 256, 0, stream>>>((const __half2*)bufA,
        (const float2*)(rT + 0 * NR * B), (__half2*)bufB, sorted2, n_hop, 1, n_e, n_t);
    hipMemsetAsync(bufA, 0, bytes, stream);
    hop_merge_kernel<<<hblocks, 256, 0, stream>>>((const __half2*)bufB,
        (const float2*)(rT + 1 * NR * B), (__half2*)bufA, sorted2, n_hop, 2, n_e, n_t);
    hipMemsetAsync(bufB, 0, bytes, stream);
    hop_merge_kernel<<<hblocks, 256, 0, stream>>>((const __half2*)bufA,
        (const float2*)(rT + 2 * NR * B), (__half2*)bufB, sorted2, n_hop, 3, n_e, n_t);

    transpose_out_kernel<<<tblocks, 256, 0, stream>>>(bufB, out, n_e);
}